// Round 20
// baseline (72.768 us; speedup 1.0000x reference)
//
#include <hip/hip_runtime.h>
#include <hip/hip_bf16.h>

#define NSP 2304   // 48*48 spatial
#define NB  4      // batch

typedef unsigned short u16;
typedef __attribute__((ext_vector_type(8))) short short8;
typedef __attribute__((ext_vector_type(4))) float f32x4;
typedef __attribute__((ext_vector_type(4))) unsigned short u16x4;

// scale * log2(e), folded into Q at QKV-GEMM epilogue: softmax p = exp2(S)
#define K1S 0.25508040852656425f

static __device__ inline u16 f2bf(float f) {
  return __builtin_bit_cast(unsigned short, __float2bfloat16(f));
}
// packed f32x2 -> bf16x2 (RNE), single VALU inst
static __device__ inline unsigned cvtpk(float a, float b) {
  unsigned r;
  asm("v_cvt_pk_bf16_f32 %0, %1, %2" : "=v"(r) : "v"(a), "v"(b));
  return r;
}

// ---------------------------------------------------------------------------
// prep (grid-fused): blocks x<72 transpose x fp32 [b][256][2304] ->
// xT bf16 [b][2304][256]; blocks x==72 convert w_qkv+w_out fp32->bf16.
// ---------------------------------------------------------------------------
__global__ __launch_bounds__(256) void prep_fused(
    const float* __restrict__ x, const float* __restrict__ wq,
    const float* __restrict__ wo, u16* __restrict__ xT,
    u16* __restrict__ wbf) {
  const int t = threadIdx.x;
  if (blockIdx.x == 72) {  // weight conversion: 32 slices x 256 thr x 32 elems
    const int cid = blockIdx.y * 4 + blockIdx.z;  // 0..31
    const int base = cid * 8192;
#pragma unroll
    for (int i = 0; i < 8; ++i) {
      int idx = base + (i * 256 + t) * 4;
      float4 v;
      if (idx < 196608) v = *(const float4*)(wq + idx);
      else              v = *(const float4*)(wo + (idx - 196608));
      u16x4 p = {f2bf(v.x), f2bf(v.y), f2bf(v.z), f2bf(v.w)};
      *(u16x4*)(wbf + idx) = p;
    }
    return;
  }
  __shared__ float tile[32][33];
  const int n0 = blockIdx.x * 32, c0 = blockIdx.y * 32, b = blockIdx.z;
  const float* xb = x + ((size_t)b * 256 + c0) * NSP + n0;
#pragma unroll
  for (int e = t; e < 1024; e += 256) {
    int cc = e >> 5, nn = e & 31;
    tile[cc][nn] = xb[(size_t)cc * NSP + nn];
  }
  __syncthreads();
  u16* xTb = xT + ((size_t)b * NSP + n0) * 256 + c0;
#pragma unroll
  for (int e = t; e < 1024; e += 256) {
    int nn = e >> 5, cc = e & 31;
    xTb[(size_t)nn * 256 + cc] = f2bf(tile[cc][nn]);
  }
}

// ---------------------------------------------------------------------------
// bf16 MFMA GEMM: D = A (Mx256) * B[b](Nx256)^T, 64x64 tile, 4 waves.
// EPI 0: rows <256 q (pre-scaled K1S), 256..511 k -> qkT[b][n][512] bf16;
//        rows >=512 v -> vbuf[b][256][2304] bf16.
// EPI 1: fp32 out + bias.
// ---------------------------------------------------------------------------
template <int EPI>
__global__ __launch_bounds__(256) void gemm_mfma(
    const u16* __restrict__ A, const u16* __restrict__ B,
    u16* __restrict__ qkT, u16* __restrict__ vbuf,
    float* __restrict__ outf, const float* __restrict__ bias, int N) {
  __shared__ u16 As[64][264];
  __shared__ u16 Bs[64][264];
  const int t = threadIdx.x, lane = t & 63, wid = t >> 6;
  const int lo = lane & 15, g = lane >> 4;
  const int wr = wid >> 1, wc = wid & 1;
  const int row0 = blockIdx.y * 64, col0 = blockIdx.x * 64, b = blockIdx.z;

  const int sr = t >> 2, c4 = t & 3;
  const u16* Arow = A + (size_t)(row0 + sr) * 256;
  const u16* Brow = B + ((size_t)b * N + col0 + sr) * 256;
#pragma unroll
  for (int i = 0; i < 8; ++i) {
    int col = (c4 + 4 * i) * 8;
    *(uint4*)&As[sr][col] = *(const uint4*)&Arow[col];
    *(uint4*)&Bs[sr][col] = *(const uint4*)&Brow[col];
  }
  __syncthreads();

  f32x4 acc[2][2];
#pragma unroll
  for (int i = 0; i < 2; ++i)
#pragma unroll
    for (int j = 0; j < 2; ++j) acc[i][j] = (f32x4){0, 0, 0, 0};

  const int ar0 = wr * 32 + lo, br0 = wc * 32 + lo;
#pragma unroll
  for (int kk = 0; kk < 8; ++kk) {
    int kc = kk * 32 + g * 8;
    short8 a0 = *(const short8*)&As[ar0][kc];
    short8 a1 = *(const short8*)&As[ar0 + 16][kc];
    short8 b0 = *(const short8*)&Bs[br0][kc];
    short8 b1 = *(const short8*)&Bs[br0 + 16][kc];
    acc[0][0] = __builtin_amdgcn_mfma_f32_16x16x32_bf16(a0, b0, acc[0][0], 0, 0, 0);
    acc[0][1] = __builtin_amdgcn_mfma_f32_16x16x32_bf16(a0, b1, acc[0][1], 0, 0, 0);
    acc[1][0] = __builtin_amdgcn_mfma_f32_16x16x32_bf16(a1, b0, acc[1][0], 0, 0, 0);
    acc[1][1] = __builtin_amdgcn_mfma_f32_16x16x32_bf16(a1, b1, acc[1][1], 0, 0, 0);
  }

  const float qs = (EPI == 0 && row0 < 256) ? K1S : 1.0f;
#pragma unroll
  for (int m2 = 0; m2 < 2; ++m2)
#pragma unroll
    for (int n2 = 0; n2 < 2; ++n2) {
      int m = row0 + wr * 32 + m2 * 16 + g * 4;
      int n = col0 + wc * 32 + n2 * 16 + lo;
      if constexpr (EPI == 0) {
        if (row0 < 512) {  // q,k -> transposed qkT[b][n][m..m+3]
          u16x4 pk = {f2bf(acc[m2][n2][0] * qs), f2bf(acc[m2][n2][1] * qs),
                      f2bf(acc[m2][n2][2] * qs), f2bf(acc[m2][n2][3] * qs)};
          *(u16x4*)(qkT + ((size_t)b * NSP + n) * 512 + m) = pk;
        } else {           // v -> natural vbuf[b][m-512][n]
#pragma unroll
          for (int r = 0; r < 4; ++r)
            vbuf[((size_t)b * 256 + (m - 512 + r)) * NSP + n] =
                f2bf(acc[m2][n2][r]);
        }
      } else {
#pragma unroll
        for (int r = 0; r < 4; ++r)
          outf[((size_t)b * 256 + m + r) * NSP + n] =
              acc[m2][n2][r] + bias[m + r];
      }
    }
}

// ---------------------------------------------------------------------------
// MFMA flash attention, 4-WAY KEY-SPLIT, 128-query 4-wave blocks, 32 q/wave.
// 2 Q-frags/wave keeps VGPR <= 64 (m69: waves/CU halves above 64) ->
// 32-waves/CU residency cap, vs r19's 76 regs -> 16-wave cap.
// Grid 2304 = 9 blocks/CU (8 resident under 19.4 KB LDS cap).
// Block: 4 waves x 32 q, 576 keys = 9 strips of 64 (double-buffered,
// 1 barrier/strip); all 4 waves share each staged strip.
// Kt[2][64][40] / Vs[2][32][70] (perm V, single-b128 frags).
// P in-register (sigma), ones-MFMA rowsum, setprio clusters.
// Partials fp32 -> part[kp][grp][33][128]; merge combines 4.
// ---------------------------------------------------------------------------
__global__ __launch_bounds__(256, 4) void attn_mfma(
    const u16* __restrict__ qkT, const u16* __restrict__ vbuf,
    float* __restrict__ part) {
  const int jb = blockIdx.x;
  const int h  = jb & 7;
  const int q2 = jb >> 3;        // [0,288)
  const int kp = q2 & 3;
  const int q3 = q2 >> 2;        // [0,72)
  const int it = q3 % 18;
  const int b  = q3 / 18;
  const int grp = q3 * 8 + h;    // [0,576)
  const int t = threadIdx.x, lane = t & 63, w = t >> 6;
  const int lo = lane & 15, g = lane >> 4;
  const int i0 = it * 128;
  const int j0base = kp * 576;

  const u16* qkTb = qkT + (size_t)b * NSP * 512;
  const u16* vb   = vbuf + ((size_t)b * 256 + h * 32) * NSP;

  __shared__ u16 Kt[2][64][40];   // [key j][d]
  __shared__ u16 Vs[2][32][70];   // [d][permuted j]

  // two Q fragments: queries i0 + w*32 + qh*16 + lo (pre-scaled by K1S)
  short8 qf[2];
#pragma unroll
  for (int qh = 0; qh < 2; ++qh)
    qf[qh] = *(const short8*)(qkTb +
              (size_t)(i0 + w * 32 + qh * 16 + lo) * 512 + h * 32 + g * 8);

  // staging (256 thr, 64-key strips): one b128 K + one b128 V per thread
  const int kr = t >> 2, kpd = (t & 3) * 8;   // K: row j (64), d-part
  const int vr = t >> 3, vjp = (t & 7) * 8;   // V: row d (32), j-part
  const int pc0 = (vjp & ~31) | (8 * ((vjp >> 2) & 3) + 4 * ((vjp >> 4) & 1));
  const u16* ksrc = qkTb + 256 + h * 32 + kpd;           // + j*512
  const u16* vsrc = vb + (size_t)vr * NSP + vjp;         // + j0

  uint4 kv = *(const uint4*)(ksrc + (size_t)(j0base + kr) * 512);
  uint4 vv = *(const uint4*)(vsrc + j0base);
  *(uint4*)&Kt[0][kr][kpd] = kv;
  *(uint2*)&Vs[0][vr][pc0]     = make_uint2(vv.x, vv.y);
  *(uint2*)&Vs[0][vr][pc0 + 8] = make_uint2(vv.z, vv.w);
  __syncthreads();

  short8 ones;
#pragma unroll
  for (int e = 0; e < 8; ++e) ones[e] = (short)0x3F80;  // bf16 1.0

  f32x4 a0[2], a1[2], al[2];
#pragma unroll
  for (int qh = 0; qh < 2; ++qh) {
    a0[qh] = (f32x4){0, 0, 0, 0};
    a1[qh] = (f32x4){0, 0, 0, 0};
    al[qh] = (f32x4){0, 0, 0, 0};
  }

  for (int s = 0; s < 9; ++s) {
    const int cur = s & 1;
    if (s + 1 < 9) {  // prefetch next strip into regs
      const int j0n = j0base + (s + 1) * 64;
      kv = *(const uint4*)(ksrc + (size_t)(j0n + kr) * 512);
      vv = *(const uint4*)(vsrc + j0n);
    }

    short8 kf0 = *(const short8*)&Kt[cur][lo][g * 8];
    short8 kf1 = *(const short8*)&Kt[cur][16 + lo][g * 8];
    short8 kf2 = *(const short8*)&Kt[cur][32 + lo][g * 8];
    short8 kf3 = *(const short8*)&Kt[cur][48 + lo][g * 8];
    short8 vf00 = *(const short8*)&Vs[cur][lo][8 * g];
    short8 vf01 = *(const short8*)&Vs[cur][lo][32 + 8 * g];
    short8 vf10 = *(const short8*)&Vs[cur][16 + lo][8 * g];
    short8 vf11 = *(const short8*)&Vs[cur][16 + lo][32 + 8 * g];

#pragma unroll
    for (int qh = 0; qh < 2; ++qh) {
      __builtin_amdgcn_s_setprio(1);
      f32x4 sv0 = __builtin_amdgcn_mfma_f32_16x16x32_bf16(kf0, qf[qh], (f32x4){0,0,0,0}, 0, 0, 0);
      f32x4 sv1 = __builtin_amdgcn_mfma_f32_16x16x32_bf16(kf1, qf[qh], (f32x4){0,0,0,0}, 0, 0, 0);
      f32x4 sv2 = __builtin_amdgcn_mfma_f32_16x16x32_bf16(kf2, qf[qh], (f32x4){0,0,0,0}, 0, 0, 0);
      f32x4 sv3 = __builtin_amdgcn_mfma_f32_16x16x32_bf16(kf3, qf[qh], (f32x4){0,0,0,0}, 0, 0, 0);
      __builtin_amdgcn_s_setprio(0);

      f32x4 e0, e1, e2, e3;
#pragma unroll
      for (int r = 0; r < 4; ++r) {
        e0[r] = __builtin_amdgcn_exp2f(sv0[r]);
        e1[r] = __builtin_amdgcn_exp2f(sv1[r]);
        e2[r] = __builtin_amdgcn_exp2f(sv2[r]);
        e3[r] = __builtin_amdgcn_exp2f(sv3[r]);
      }
      uint4 P0 = {cvtpk(e0[0], e0[1]), cvtpk(e0[2], e0[3]),
                  cvtpk(e1[0], e1[1]), cvtpk(e1[2], e1[3])};
      uint4 P1 = {cvtpk(e2[0], e2[1]), cvtpk(e2[2], e2[3]),
                  cvtpk(e3[0], e3[1]), cvtpk(e3[2], e3[3])};
      short8 pf0 = __builtin_bit_cast(short8, P0);
      short8 pf1 = __builtin_bit_cast(short8, P1);

      __builtin_amdgcn_s_setprio(1);
      a0[qh] = __builtin_amdgcn_mfma_f32_16x16x32_bf16(pf0, vf00, a0[qh], 0, 0, 0);
      a1[qh] = __builtin_amdgcn_mfma_f32_16x16x32_bf16(pf0, vf10, a1[qh], 0, 0, 0);
      al[qh] = __builtin_amdgcn_mfma_f32_16x16x32_bf16(pf0, ones, al[qh], 0, 0, 0);
      a0[qh] = __builtin_amdgcn_mfma_f32_16x16x32_bf16(pf1, vf01, a0[qh], 0, 0, 0);
      a1[qh] = __builtin_amdgcn_mfma_f32_16x16x32_bf16(pf1, vf11, a1[qh], 0, 0, 0);
      al[qh] = __builtin_amdgcn_mfma_f32_16x16x32_bf16(pf1, ones, al[qh], 0, 0, 0);
      __builtin_amdgcn_s_setprio(0);
    }

    if (s + 1 < 9) {  // write next strip into the other buffer
      *(uint4*)&Kt[cur ^ 1][kr][kpd] = kv;
      *(uint2*)&Vs[cur ^ 1][vr][pc0]     = make_uint2(vv.x, vv.y);
      *(uint2*)&Vs[cur ^ 1][vr][pc0 + 8] = make_uint2(vv.z, vv.w);
    }
    __syncthreads();
  }

  // ---- write fp32 partials: part[kp][grp][col 0..32][row 0..127] ----
  float* pg = part + ((size_t)(kp * 576 + grp)) * (33 * 128);
#pragma unroll
  for (int qh = 0; qh < 2; ++qh) {
    int row = w * 32 + qh * 16 + g * 4;
    *(f32x4*)&pg[(size_t)lo * 128 + row]        = a0[qh];
    *(f32x4*)&pg[(size_t)(16 + lo) * 128 + row] = a1[qh];
    if (lo == 0) *(f32x4*)&pg[(size_t)32 * 128 + row] = al[qh];
  }
}

// ---------------------------------------------------------------------------
// merge: out[row][c] = (sum_kp p[c][row]) / (sum_kp l[row]) -> attnoT bf16.
// Grid 576 (one per grp, grp%8=h preserves XCD locality), 128 thr (1/row).
// ---------------------------------------------------------------------------
__global__ __launch_bounds__(128) void merge_attn(
    const float* __restrict__ part, u16* __restrict__ attnoT) {
  const int grp = blockIdx.x;
  const int h = grp & 7, q3 = grp >> 3;
  const int it = q3 % 18, b = q3 / 18;
  const int t = threadIdx.x;  // row 0..127
  const float* p0 = part + (size_t)grp * (33 * 128);
  const size_t stride = (size_t)576 * 33 * 128;
  float lsum = 0.0f;
#pragma unroll
  for (int kp = 0; kp < 4; ++kp) lsum += p0[kp * stride + 32 * 128 + t];
  float inv = 1.0f / lsum;
  u16* ob = attnoT + ((size_t)b * NSP + it * 128 + t) * 256 + h * 32;
#pragma unroll
  for (int c4 = 0; c4 < 8; ++c4) {
    u16x4 o;
#pragma unroll
    for (int j = 0; j < 4; ++j) {
      int c = c4 * 4 + j;
      float v = 0.0f;
#pragma unroll
      for (int kp = 0; kp < 4; ++kp) v += p0[kp * stride + c * 128 + t];
      o[j] = f2bf(v * inv);
    }
    *(u16x4*)&ob[c4 * 4] = o;
  }
}

// ---------------------------------------------------------------------------
extern "C" void kernel_launch(void* const* d_in, const int* in_sizes, int n_in,
                              void* d_out, int out_size, void* d_ws, size_t ws_size,
                              hipStream_t stream) {
  const float* x     = (const float*)d_in[0];  // [4][256][48][48]
  const float* w_qkv = (const float*)d_in[1];  // [768][256]
  const float* w_out = (const float*)d_in[2];  // [256][256]
  const float* b_out = (const float*)d_in[3];  // [256]
  float* out = (float*)d_out;                  // [4][256][2304]

  u16* wbf    = (u16*)d_ws;                    // wqkv 196608 then wout 65536
  u16* xT     = wbf + 262144;                  // [4][2304][256]
  u16* qkT    = xT + (size_t)NB * NSP * 256;   // [4][2304][512]
  u16* vbuf   = qkT + (size_t)NB * NSP * 512;  // [4][256][2304]
  u16* attnoT = vbuf + (size_t)NB * 256 * NSP; // [4][2304][256]
  float* part = (float*)(attnoT + (size_t)NB * NSP * 256);  // [4][576][33][128]

  dim3 blk(256);
  prep_fused<<<dim3(73, 8, NB), blk, 0, stream>>>(x, w_qkv, w_out, xT, wbf);
  gemm_mfma<0><<<dim3(NSP / 64, 12, NB), blk, 0, stream>>>(
      wbf, xT, qkT, vbuf, nullptr, nullptr, NSP);
  attn_mfma<<<dim3(2304), blk, 0, stream>>>(qkT, vbuf, part);
  merge_attn<<<dim3(576), dim3(128), 0, stream>>>(part, attnoT);
  gemm_mfma<1><<<dim3(NSP / 64, 4, NB), blk, 0, stream>>>(
      wbf + 196608, attnoT, nullptr, nullptr, out, b_out, NSP);
}

// Round 21
// 67.496 us; speedup vs baseline: 1.0781x; 1.0781x over previous
//
#include <hip/hip_runtime.h>
#include <hip/hip_bf16.h>

#define NSP 2304   // 48*48 spatial
#define NB  4      // batch

typedef unsigned short u16;
typedef __attribute__((ext_vector_type(8))) short short8;
typedef __attribute__((ext_vector_type(4))) float f32x4;
typedef __attribute__((ext_vector_type(4))) unsigned short u16x4;

// scale * log2(e), folded into Q at QKV-GEMM epilogue: softmax p = exp2(S)
#define K1S 0.25508040852656425f

static __device__ inline u16 f2bf(float f) {
  return __builtin_bit_cast(unsigned short, __float2bfloat16(f));
}
static __device__ inline float bf2f(u16 v) {
  unsigned u = ((unsigned)v) << 16;
  return __builtin_bit_cast(float, u);
}
// packed f32x2 -> bf16x2 (RNE), single VALU inst; lo16=cvt(a), hi16=cvt(b)
static __device__ inline unsigned cvtpk(float a, float b) {
  unsigned r;
  asm("v_cvt_pk_bf16_f32 %0, %1, %2" : "=v"(r) : "v"(a), "v"(b));
  return r;
}

// ---------------------------------------------------------------------------
// prep (grid-fused): blocks x<72 transpose x fp32 [b][256][2304] ->
// xT bf16 [b][2304][256]; blocks x==72 convert w_qkv+w_out fp32->bf16.
// ---------------------------------------------------------------------------
__global__ __launch_bounds__(256) void prep_fused(
    const float* __restrict__ x, const float* __restrict__ wq,
    const float* __restrict__ wo, u16* __restrict__ xT,
    u16* __restrict__ wbf) {
  const int t = threadIdx.x;
  if (blockIdx.x == 72) {  // weight conversion: 32 slices x 256 thr x 32 elems
    const int cid = blockIdx.y * 4 + blockIdx.z;  // 0..31
    const int base = cid * 8192;
#pragma unroll
    for (int i = 0; i < 8; ++i) {
      int idx = base + (i * 256 + t) * 4;
      float4 v;
      if (idx < 196608) v = *(const float4*)(wq + idx);
      else              v = *(const float4*)(wo + (idx - 196608));
      u16x4 p = {f2bf(v.x), f2bf(v.y), f2bf(v.z), f2bf(v.w)};
      *(u16x4*)(wbf + idx) = p;
    }
    return;
  }
  __shared__ float tile[32][33];
  const int n0 = blockIdx.x * 32, c0 = blockIdx.y * 32, b = blockIdx.z;
  const float* xb = x + ((size_t)b * 256 + c0) * NSP + n0;
#pragma unroll
  for (int e = t; e < 1024; e += 256) {
    int cc = e >> 5, nn = e & 31;
    tile[cc][nn] = xb[(size_t)cc * NSP + nn];
  }
  __syncthreads();
  u16* xTb = xT + ((size_t)b * NSP + n0) * 256 + c0;
#pragma unroll
  for (int e = t; e < 1024; e += 256) {
    int nn = e >> 5, cc = e & 31;
    xTb[(size_t)nn * 256 + cc] = f2bf(tile[cc][nn]);
  }
}

// ---------------------------------------------------------------------------
// bf16 MFMA GEMM: D = A (Mx256) * B[b](Nx256)^T, 64x64 tile, 4 waves.
// EPI 0: rows <256 q (pre-scaled K1S), 256..511 k -> qkT[b][n][512] bf16;
//        rows >=512 v -> vbuf[b][256][2304] bf16.
// EPI 1: fp32 out + bias.
// ---------------------------------------------------------------------------
template <int EPI>
__global__ __launch_bounds__(256) void gemm_mfma(
    const u16* __restrict__ A, const u16* __restrict__ B,
    u16* __restrict__ qkT, u16* __restrict__ vbuf,
    float* __restrict__ outf, const float* __restrict__ bias, int N) {
  __shared__ u16 As[64][264];
  __shared__ u16 Bs[64][264];
  const int t = threadIdx.x, lane = t & 63, wid = t >> 6;
  const int lo = lane & 15, g = lane >> 4;
  const int wr = wid >> 1, wc = wid & 1;
  const int row0 = blockIdx.y * 64, col0 = blockIdx.x * 64, b = blockIdx.z;

  const int sr = t >> 2, c4 = t & 3;
  const u16* Arow = A + (size_t)(row0 + sr) * 256;
  const u16* Brow = B + ((size_t)b * N + col0 + sr) * 256;
#pragma unroll
  for (int i = 0; i < 8; ++i) {
    int col = (c4 + 4 * i) * 8;
    *(uint4*)&As[sr][col] = *(const uint4*)&Arow[col];
    *(uint4*)&Bs[sr][col] = *(const uint4*)&Brow[col];
  }
  __syncthreads();

  f32x4 acc[2][2];
#pragma unroll
  for (int i = 0; i < 2; ++i)
#pragma unroll
    for (int j = 0; j < 2; ++j) acc[i][j] = (f32x4){0, 0, 0, 0};

  const int ar0 = wr * 32 + lo, br0 = wc * 32 + lo;
#pragma unroll
  for (int kk = 0; kk < 8; ++kk) {
    int kc = kk * 32 + g * 8;
    short8 a0 = *(const short8*)&As[ar0][kc];
    short8 a1 = *(const short8*)&As[ar0 + 16][kc];
    short8 b0 = *(const short8*)&Bs[br0][kc];
    short8 b1 = *(const short8*)&Bs[br0 + 16][kc];
    acc[0][0] = __builtin_amdgcn_mfma_f32_16x16x32_bf16(a0, b0, acc[0][0], 0, 0, 0);
    acc[0][1] = __builtin_amdgcn_mfma_f32_16x16x32_bf16(a0, b1, acc[0][1], 0, 0, 0);
    acc[1][0] = __builtin_amdgcn_mfma_f32_16x16x32_bf16(a1, b0, acc[1][0], 0, 0, 0);
    acc[1][1] = __builtin_amdgcn_mfma_f32_16x16x32_bf16(a1, b1, acc[1][1], 0, 0, 0);
  }

  const float qs = (EPI == 0 && row0 < 256) ? K1S : 1.0f;
#pragma unroll
  for (int m2 = 0; m2 < 2; ++m2)
#pragma unroll
    for (int n2 = 0; n2 < 2; ++n2) {
      int m = row0 + wr * 32 + m2 * 16 + g * 4;
      int n = col0 + wc * 32 + n2 * 16 + lo;
      if constexpr (EPI == 0) {
        if (row0 < 512) {  // q,k -> transposed qkT[b][n][m..m+3]
          u16x4 pk = {f2bf(acc[m2][n2][0] * qs), f2bf(acc[m2][n2][1] * qs),
                      f2bf(acc[m2][n2][2] * qs), f2bf(acc[m2][n2][3] * qs)};
          *(u16x4*)(qkT + ((size_t)b * NSP + n) * 512 + m) = pk;
        } else {           // v -> natural vbuf[b][m-512][n]
#pragma unroll
          for (int r = 0; r < 4; ++r)
            vbuf[((size_t)b * 256 + (m - 512 + r)) * NSP + n] =
                f2bf(acc[m2][n2][r]);
        }
      } else {
#pragma unroll
        for (int r = 0; r < 4; ++r)
          outf[((size_t)b * 256 + m + r) * NSP + n] =
              acc[m2][n2][r] + bias[m + r];
      }
    }
}

// ---------------------------------------------------------------------------
// MFMA flash attention, 4-WAY KEY-SPLIT, 192-query 4-wave blocks (r19 body).
// Grid 1536: h=jb&7 (XCD), kp=key-quarter, it (12 tiles of 192 q), b.
// Block: 4 waves x 48 q, 576 keys = 9 strips of 64 (double-buffered,
// 1 barrier/strip); all 4 waves share each staged strip.
// Kt[2][64][40] / Vs[2][32][70] (perm V, single-b128 frags) = 19.2 KB.
// __launch_bounds__(256, 4): VGPR cap 128 (kernel needs ~76; (256,6)
// spilled at cap 40 in r18). P in-register (sigma), ones-MFMA rowsum,
// setprio clusters.
// Partials: O in BF16 -> opart[kp][grp][32][192] (halves traffic vs r19's
// fp32); l row-sums stay fp32 -> lpart[kp][grp][192].
// ---------------------------------------------------------------------------
__global__ __launch_bounds__(256, 4) void attn_mfma(
    const u16* __restrict__ qkT, const u16* __restrict__ vbuf,
    u16* __restrict__ opart, float* __restrict__ lpart) {
  const int jb = blockIdx.x;
  const int h  = jb & 7;
  const int q2 = jb >> 3;        // [0,192)
  const int kp = q2 & 3;
  const int q3 = q2 >> 2;        // [0,48)
  const int it = q3 % 12;
  const int b  = q3 / 12;
  const int grp = q3 * 8 + h;    // [0,384)
  const int t = threadIdx.x, lane = t & 63, w = t >> 6;
  const int lo = lane & 15, g = lane >> 4;
  const int i0 = it * 192;
  const int j0base = kp * 576;

  const u16* qkTb = qkT + (size_t)b * NSP * 512;
  const u16* vb   = vbuf + ((size_t)b * 256 + h * 32) * NSP;

  __shared__ u16 Kt[2][64][40];   // [key j][d]
  __shared__ u16 Vs[2][32][70];   // [d][permuted j]

  // three Q fragments: queries i0 + w*48 + qh*16 + lo (pre-scaled by K1S)
  short8 qf[3];
#pragma unroll
  for (int qh = 0; qh < 3; ++qh)
    qf[qh] = *(const short8*)(qkTb +
              (size_t)(i0 + w * 48 + qh * 16 + lo) * 512 + h * 32 + g * 8);

  // staging (256 thr, 64-key strips): one b128 K + one b128 V per thread
  const int kr = t >> 2, kpd = (t & 3) * 8;   // K: row j (64), d-part
  const int vr = t >> 3, vjp = (t & 7) * 8;   // V: row d (32), j-part
  const int pc0 = (vjp & ~31) | (8 * ((vjp >> 2) & 3) + 4 * ((vjp >> 4) & 1));
  const u16* ksrc = qkTb + 256 + h * 32 + kpd;           // + j*512
  const u16* vsrc = vb + (size_t)vr * NSP + vjp;         // + j0

  uint4 kv = *(const uint4*)(ksrc + (size_t)(j0base + kr) * 512);
  uint4 vv = *(const uint4*)(vsrc + j0base);
  *(uint4*)&Kt[0][kr][kpd] = kv;
  *(uint2*)&Vs[0][vr][pc0]     = make_uint2(vv.x, vv.y);
  *(uint2*)&Vs[0][vr][pc0 + 8] = make_uint2(vv.z, vv.w);
  __syncthreads();

  short8 ones;
#pragma unroll
  for (int e = 0; e < 8; ++e) ones[e] = (short)0x3F80;  // bf16 1.0

  f32x4 a0[3], a1[3], al[3];
#pragma unroll
  for (int qh = 0; qh < 3; ++qh) {
    a0[qh] = (f32x4){0, 0, 0, 0};
    a1[qh] = (f32x4){0, 0, 0, 0};
    al[qh] = (f32x4){0, 0, 0, 0};
  }

  for (int s = 0; s < 9; ++s) {
    const int cur = s & 1;
    if (s + 1 < 9) {  // prefetch next strip into regs
      const int j0n = j0base + (s + 1) * 64;
      kv = *(const uint4*)(ksrc + (size_t)(j0n + kr) * 512);
      vv = *(const uint4*)(vsrc + j0n);
    }

    short8 kf0 = *(const short8*)&Kt[cur][lo][g * 8];
    short8 kf1 = *(const short8*)&Kt[cur][16 + lo][g * 8];
    short8 kf2 = *(const short8*)&Kt[cur][32 + lo][g * 8];
    short8 kf3 = *(const short8*)&Kt[cur][48 + lo][g * 8];
    short8 vf00 = *(const short8*)&Vs[cur][lo][8 * g];
    short8 vf01 = *(const short8*)&Vs[cur][lo][32 + 8 * g];
    short8 vf10 = *(const short8*)&Vs[cur][16 + lo][8 * g];
    short8 vf11 = *(const short8*)&Vs[cur][16 + lo][32 + 8 * g];

#pragma unroll
    for (int qh = 0; qh < 3; ++qh) {
      __builtin_amdgcn_s_setprio(1);
      f32x4 sv0 = __builtin_amdgcn_mfma_f32_16x16x32_bf16(kf0, qf[qh], (f32x4){0,0,0,0}, 0, 0, 0);
      f32x4 sv1 = __builtin_amdgcn_mfma_f32_16x16x32_bf16(kf1, qf[qh], (f32x4){0,0,0,0}, 0, 0, 0);
      f32x4 sv2 = __builtin_amdgcn_mfma_f32_16x16x32_bf16(kf2, qf[qh], (f32x4){0,0,0,0}, 0, 0, 0);
      f32x4 sv3 = __builtin_amdgcn_mfma_f32_16x16x32_bf16(kf3, qf[qh], (f32x4){0,0,0,0}, 0, 0, 0);
      __builtin_amdgcn_s_setprio(0);

      f32x4 e0, e1, e2, e3;
#pragma unroll
      for (int r = 0; r < 4; ++r) {
        e0[r] = __builtin_amdgcn_exp2f(sv0[r]);
        e1[r] = __builtin_amdgcn_exp2f(sv1[r]);
        e2[r] = __builtin_amdgcn_exp2f(sv2[r]);
        e3[r] = __builtin_amdgcn_exp2f(sv3[r]);
      }
      uint4 P0 = {cvtpk(e0[0], e0[1]), cvtpk(e0[2], e0[3]),
                  cvtpk(e1[0], e1[1]), cvtpk(e1[2], e1[3])};
      uint4 P1 = {cvtpk(e2[0], e2[1]), cvtpk(e2[2], e2[3]),
                  cvtpk(e3[0], e3[1]), cvtpk(e3[2], e3[3])};
      short8 pf0 = __builtin_bit_cast(short8, P0);
      short8 pf1 = __builtin_bit_cast(short8, P1);

      __builtin_amdgcn_s_setprio(1);
      a0[qh] = __builtin_amdgcn_mfma_f32_16x16x32_bf16(pf0, vf00, a0[qh], 0, 0, 0);
      a1[qh] = __builtin_amdgcn_mfma_f32_16x16x32_bf16(pf0, vf10, a1[qh], 0, 0, 0);
      al[qh] = __builtin_amdgcn_mfma_f32_16x16x32_bf16(pf0, ones, al[qh], 0, 0, 0);
      a0[qh] = __builtin_amdgcn_mfma_f32_16x16x32_bf16(pf1, vf01, a0[qh], 0, 0, 0);
      a1[qh] = __builtin_amdgcn_mfma_f32_16x16x32_bf16(pf1, vf11, a1[qh], 0, 0, 0);
      al[qh] = __builtin_amdgcn_mfma_f32_16x16x32_bf16(pf1, ones, al[qh], 0, 0, 0);
      __builtin_amdgcn_s_setprio(0);
    }

    if (s + 1 < 9) {  // write next strip into the other buffer
      *(uint4*)&Kt[cur ^ 1][kr][kpd] = kv;
      *(uint2*)&Vs[cur ^ 1][vr][pc0]     = make_uint2(vv.x, vv.y);
      *(uint2*)&Vs[cur ^ 1][vr][pc0 + 8] = make_uint2(vv.z, vv.w);
    }
    __syncthreads();
  }

  // ---- write partials: O bf16 -> opart[kp][grp][col 0..31][row 0..191],
  //      l fp32 -> lpart[kp][grp][row] ----
  u16* pg = opart + ((size_t)(kp * 384 + grp)) * (32 * 192);
  float* lg = lpart + ((size_t)(kp * 384 + grp)) * 192;
#pragma unroll
  for (int qh = 0; qh < 3; ++qh) {
    int row = w * 48 + qh * 16 + g * 4;
    uint2 o0 = make_uint2(cvtpk(a0[qh][0], a0[qh][1]),
                          cvtpk(a0[qh][2], a0[qh][3]));
    uint2 o1 = make_uint2(cvtpk(a1[qh][0], a1[qh][1]),
                          cvtpk(a1[qh][2], a1[qh][3]));
    *(uint2*)&pg[(size_t)lo * 192 + row]        = o0;
    *(uint2*)&pg[(size_t)(16 + lo) * 192 + row] = o1;
    if (lo == 0) *(f32x4*)&lg[row] = al[qh];
  }
}

// ---------------------------------------------------------------------------
// merge: out[row][c] = (sum_kp p[c][row]) / (sum_kp l[row]) -> attnoT bf16.
// Grid 384 (one per grp, grp%8=h preserves XCD locality), 192 thr (1/row).
// ---------------------------------------------------------------------------
__global__ __launch_bounds__(192) void merge_attn(
    const u16* __restrict__ opart, const float* __restrict__ lpart,
    u16* __restrict__ attnoT) {
  const int grp = blockIdx.x;
  const int h = grp & 7, q3 = grp >> 3;
  const int it = q3 % 12, b = q3 / 12;
  const int t = threadIdx.x;  // row 0..191
  const u16* p0 = opart + (size_t)grp * (32 * 192);
  const float* l0 = lpart + (size_t)grp * 192;
  const size_t ostride = (size_t)384 * 32 * 192;
  const size_t lstride = (size_t)384 * 192;
  float lsum = 0.0f;
#pragma unroll
  for (int kp = 0; kp < 4; ++kp) lsum += l0[kp * lstride + t];
  float inv = 1.0f / lsum;
  u16* ob = attnoT + ((size_t)b * NSP + it * 192 + t) * 256 + h * 32;
#pragma unroll
  for (int c4 = 0; c4 < 8; ++c4) {
    u16x4 o;
#pragma unroll
    for (int j = 0; j < 4; ++j) {
      int c = c4 * 4 + j;
      float v = 0.0f;
#pragma unroll
      for (int kp = 0; kp < 4; ++kp)
        v += bf2f(p0[kp * ostride + (size_t)c * 192 + t]);
      o[j] = f2bf(v * inv);
    }
    *(u16x4*)&ob[c4 * 4] = o;
  }
}

// ---------------------------------------------------------------------------
extern "C" void kernel_launch(void* const* d_in, const int* in_sizes, int n_in,
                              void* d_out, int out_size, void* d_ws, size_t ws_size,
                              hipStream_t stream) {
  const float* x     = (const float*)d_in[0];  // [4][256][48][48]
  const float* w_qkv = (const float*)d_in[1];  // [768][256]
  const float* w_out = (const float*)d_in[2];  // [256][256]
  const float* b_out = (const float*)d_in[3];  // [256]
  float* out = (float*)d_out;                  // [4][256][2304]

  u16* wbf    = (u16*)d_ws;                    // wqkv 196608 then wout 65536
  u16* xT     = wbf + 262144;                  // [4][2304][256]
  u16* qkT    = xT + (size_t)NB * NSP * 256;   // [4][2304][512]
  u16* vbuf   = qkT + (size_t)NB * NSP * 512;  // [4][256][2304]
  u16* attnoT = vbuf + (size_t)NB * 256 * NSP; // [4][2304][256]
  u16* opart  = attnoT + (size_t)NB * NSP * 256;      // [4][384][32][192] bf16
  float* lpart = (float*)(opart + (size_t)4 * 384 * 32 * 192);  // [4][384][192]

  dim3 blk(256);
  prep_fused<<<dim3(73, 8, NB), blk, 0, stream>>>(x, w_qkv, w_out, xT, wbf);
  gemm_mfma<0><<<dim3(NSP / 64, 12, NB), blk, 0, stream>>>(
      wbf, xT, qkT, vbuf, nullptr, nullptr, NSP);
  attn_mfma<<<dim3(1536), blk, 0, stream>>>(qkT, vbuf, opart, lpart);
  merge_attn<<<dim3(384), dim3(192), 0, stream>>>(opart, lpart, attnoT);
  gemm_mfma<1><<<dim3(NSP / 64, 4, NB), blk, 0, stream>>>(
      wbf + 196608, attnoT, nullptr, nullptr, out, b_out, NSP);
}